// Round 12
// baseline (190.803 us; speedup 1.0000x reference)
//
#include <hip/hip_runtime.h>
#include <math.h>

// SpaceFillingVQ: N=65536 rows, D=64, E=4096 entries.
// bf16-split (3-term) MFMA distance pass, 64 rows/wave (4 row-groups sharing
// each B-fragment ds_read -> 24 MFMA per ds_read), E in 4 slices (16 waves/CU),
// 4-buffer 3-deep counted-vmcnt global_load_lds pipeline. fp32 rescue gap<TAU.

constexpr int D = 64;
constexpr int CHUNK = 32;           // entries per pipeline stage
constexpr int NTILES = CHUNK / 16;  // 2 MFMA tiles per chunk
constexpr int E_PAD = 4096;
constexpr int ESLICES = 4;
constexpr int SLICE = E_PAD / ESLICES;  // 1024 entries per slice
constexpr int NCH = SLICE / CHUNK;      // 32 chunks per slice
constexpr int NRG = 4;              // row-groups per wave (64 rows)
constexpr float TAU = 0.01f;
constexpr int NSLICE = 8;
constexpr int SLICE_E = E_PAD / NSLICE;
constexpr int BLK = 256;            // 4 waves; each wave owns 64 rows

typedef __attribute__((ext_vector_type(8))) short bf16x8;
typedef __attribute__((ext_vector_type(4))) float f32x4;

__device__ inline unsigned short f2bf(float x) {  // round-to-nearest-even bf16
  unsigned int u = __float_as_uint(x);
  u = (u + 0x7fffu + ((u >> 16) & 1u)) >> 16;
  return (unsigned short)u;
}
__device__ inline float bf2f(unsigned short h) {
  return __uint_as_float(((unsigned int)h) << 16);
}

__device__ __forceinline__ void gll16(const void* g, void* l) {
  __builtin_amdgcn_global_load_lds(
      (const __attribute__((address_space(1))) unsigned int*)g,
      (__attribute__((address_space(3))) unsigned int*)l, 16, 0, 0);
}

// ---------------- Kernel 1: dithered codebook (f32 + bf16 hi/lo split) + c2/2 ----
__global__ __launch_bounds__(64) void build_kernel(
    const float* __restrict__ cb, const float* __restrict__ dither,
    float* __restrict__ dcb, unsigned short* __restrict__ dcbh,
    unsigned short* __restrict__ dcbl, float* __restrict__ c2h,
    float* __restrict__ counts, int* __restrict__ rescue_n, int E, int Em1) {
  int i = blockIdx.x;
  int k = threadIdx.x;
  if (k == 0) counts[i] = 0.0f;
  if (i == 0 && k == 1) *rescue_n = 0;
  if (i >= Em1) {  // pad entries: never selectable
    dcb[(size_t)i * D + k] = 0.f;
    dcbh[(size_t)i * D + k] = 0;
    dcbl[(size_t)i * D + k] = 0;
    if (k == 0) c2h[i] = 3.0e38f;
    return;
  }
  float frac = dither[i] + (float)i;  // replicate reference f32 arithmetic
  int ii = (int)floorf(frac);
  ii = max(0, min(ii, E - 2));
  float r = frac - (float)ii;
  float v = (1.0f - r) * cb[(size_t)ii * D + k] + r * cb[(size_t)(ii + 1) * D + k];
  dcb[(size_t)i * D + k] = v;
  unsigned short h = f2bf(v);
  unsigned short l = f2bf(v - bf2f(h));
  dcbh[(size_t)i * D + k] = h;
  dcbl[(size_t)i * D + k] = l;
  float s = v * v;
#pragma unroll
  for (int off = 32; off > 0; off >>= 1) s += __shfl_down(s, off, 64);
  if (k == 0) c2h[i] = 0.5f * s;
}

// ---------------- Kernel 2: MFMA distance over one E-slice --------------------
// grid (N/256, 4); block 256 = 4 waves; 64 rows/wave (4 row-groups of 16).
// 3-deep counted-vmcnt pipeline across 4 LDS buffers.
__global__ __launch_bounds__(BLK, 3) void vq_mfma_kernel(
    const float* __restrict__ X, const unsigned short* __restrict__ dcbh,
    const unsigned short* __restrict__ dcbl, const float* __restrict__ c2h,
    float* __restrict__ out_b1, int* __restrict__ out_i1,
    float* __restrict__ out_b2, int N) {
  __shared__ unsigned short s_h[4][CHUNK * D];  // 4 x 4KB
  __shared__ unsigned short s_l[4][CHUNK * D];  // 4 x 4KB
  __shared__ float s_c2all[SLICE];              // 4KB, loaded once

  const int tid = threadIdx.x;
  const int lane = tid & 63;
  const int wv = tid >> 6;
  const int col = lane & 15;   // MFMA col / A-row within 16
  const int kg = lane >> 4;    // k-group 0..3
  const int slice = blockIdx.y;
  const int sbase = slice * SLICE;
  const int wvbase = blockIdx.x * 256 + wv * 64;

  // ---- A fragments for 4 row-groups: bf16 hi/lo, 2 K-halves (k 0-31, 32-63)
  bf16x8 ah0[NRG], ah1[NRG], al0[NRG], al1[NRG];
#pragma unroll
  for (int rg = 0; rg < NRG; ++rg) {
    const float* xp = X + (size_t)(wvbase + rg * 16 + col) * D + kg * 8;
#pragma unroll
    for (int i = 0; i < 8; ++i) {
      float x0 = xp[i], x1 = xp[32 + i];
      unsigned short h0 = f2bf(x0), h1 = f2bf(x1);
      ah0[rg][i] = (short)h0; ah1[rg][i] = (short)h1;
      al0[rg][i] = (short)f2bf(x0 - bf2f(h0));
      al1[rg][i] = (short)f2bf(x1 - bf2f(h1));
    }
  }

  // ---- c2/2 for the whole slice -> LDS once (keeps loop vmcnt queue pure)
  for (int i = tid; i < SLICE; i += BLK) s_c2all[i] = c2h[sbase + i];

  float b1[NRG][4], b2[NRG][4];
  int i1[NRG][4];
#pragma unroll
  for (int rg = 0; rg < NRG; ++rg)
#pragma unroll
    for (int r = 0; r < 4; ++r) { b1[rg][r] = -3.4e38f; b2[rg][r] = -3.4e38f; i1[rg][r] = sbase; }

  const int xs = col & 7;  // XOR-swizzle key (entry&7 within tile == col&7)

  // staging: pre-swizzled GLOBAL source + linear LDS dest (rule #21).
  // 256 16B-units per chunk per array; wave wv covers units [wv*64 + lane]
  // -> exactly 2 gll16 per wave per chunk (uniform vmcnt accounting).
  auto stage = [&](int ch, int buf) {
    const int u = wv * 64 + lane;
    const int e = u >> 3, g = u & 7;
    const size_t goff = (((size_t)(sbase + ch * CHUNK + e)) << 6) + ((g ^ (e & 7)) << 3);
    gll16(dcbh + goff, (char*)s_h[buf] + (size_t)wv * 1024);  // +lane*16 by HW
    gll16(dcbl + goff, (char*)s_l[buf] + (size_t)wv * 1024);
  };

  __syncthreads();  // c2 preload visible to all waves (full drain, pre-pipeline)

  stage(0, 0);
  stage(1, 1);
  stage(2, 2);

  for (int ch = 0; ch < NCH; ++ch) {
    // counted wait: own chunk-ch loads (oldest 2) done; deeper prefetches in flight
    if (ch < NCH - 2)       asm volatile("s_waitcnt vmcnt(4)" ::: "memory");
    else if (ch == NCH - 2) asm volatile("s_waitcnt vmcnt(2)" ::: "memory");
    else                    asm volatile("s_waitcnt vmcnt(0)" ::: "memory");
    __builtin_amdgcn_s_barrier();  // all waves' ch-loads landed

    const int cur = ch & 3;
    const int ebase = sbase + ch * CHUNK;
    const int c2base = ch * CHUNK;

#pragma unroll
    for (int t = 0; t < NTILES; ++t) {
      const int el = t * 16 + col;
      const char* bb = (const char*)s_h[cur] + el * 128;
      const char* ll = (const char*)s_l[cur] + el * 128;
      bf16x8 bh0 = *(const bf16x8*)(bb + ((kg ^ xs) << 4));
      bf16x8 bh1 = *(const bf16x8*)(bb + (((kg + 4) ^ xs) << 4));
      bf16x8 bl0 = *(const bf16x8*)(ll + ((kg ^ xs) << 4));
      bf16x8 bl1 = *(const bf16x8*)(ll + (((kg + 4) ^ xs) << 4));
      float hc2 = s_c2all[c2base + el];
      int colg = ebase + el;
#pragma unroll
      for (int rg = 0; rg < NRG; ++rg) {
        f32x4 acc = {-hc2, -hc2, -hc2, -hc2};  // preload -c2/2: s = acc directly
        acc = __builtin_amdgcn_mfma_f32_16x16x32_bf16(ah0[rg], bh0, acc, 0, 0, 0);
        acc = __builtin_amdgcn_mfma_f32_16x16x32_bf16(ah1[rg], bh1, acc, 0, 0, 0);
        acc = __builtin_amdgcn_mfma_f32_16x16x32_bf16(ah0[rg], bl0, acc, 0, 0, 0);
        acc = __builtin_amdgcn_mfma_f32_16x16x32_bf16(ah1[rg], bl1, acc, 0, 0, 0);
        acc = __builtin_amdgcn_mfma_f32_16x16x32_bf16(al0[rg], bh0, acc, 0, 0, 0);
        acc = __builtin_amdgcn_mfma_f32_16x16x32_bf16(al1[rg], bh1, acc, 0, 0, 0);
#pragma unroll
        for (int r = 0; r < 4; ++r) {
          float s = acc[r];
          bool gt = s > b1[rg][r];  // strict > -> first occurrence
          b2[rg][r] = __builtin_amdgcn_fmed3f(b2[rg][r], s, b1[rg][r]);  // b2<=b1
          b1[rg][r] = fmaxf(b1[rg][r], s);
          i1[rg][r] = gt ? colg : i1[rg][r];
        }
      }
    }

    // prefetch 3 ahead into buf[(ch+3)&3] (= buffer consumed at ch-1; all waves
    // passed barrier(ch), so no reader remains -> safe overwrite target)
    if (ch + 3 < NCH) stage(ch + 3, (ch + 3) & 3);
  }

  // cross-lane reduce over 16 cols (xor within lane&15; same row group = lane>>4)
#pragma unroll
  for (int m = 1; m < 16; m <<= 1) {
#pragma unroll
    for (int rg = 0; rg < NRG; ++rg)
#pragma unroll
      for (int r = 0; r < 4; ++r) {
        float ob1 = __shfl_xor(b1[rg][r], m, 64);
        float ob2 = __shfl_xor(b2[rg][r], m, 64);
        int oi1 = __shfl_xor(i1[rg][r], m, 64);
        float loser = fminf(b1[rg][r], ob1);
        b2[rg][r] = fmaxf(fmaxf(b2[rg][r], ob2), loser);
        bool take = (ob1 > b1[rg][r]) || (ob1 == b1[rg][r] && oi1 < i1[rg][r]);
        b1[rg][r] = take ? ob1 : b1[rg][r];
        i1[rg][r] = take ? oi1 : i1[rg][r];
      }
  }
  if (col == 0) {
#pragma unroll
    for (int rg = 0; rg < NRG; ++rg)
#pragma unroll
      for (int r = 0; r < 4; ++r) {
        int row = wvbase + rg * 16 + kg * 4 + r;  // row=(lane>>4)*4+reg (C/D map)
        size_t o = (size_t)slice * N + row;
        out_b1[o] = b1[rg][r];
        out_i1[o] = i1[rg][r];
        out_b2[o] = b2[rg][r];
      }
  }
}

// ---------------- Kernel 3: merge slices, histogram, quantized gather --------
__global__ __launch_bounds__(64) void finish_kernel(
    const float* __restrict__ out_b1, const int* __restrict__ out_i1,
    const float* __restrict__ out_b2,
    const float* __restrict__ dcb, float* __restrict__ outq,
    float* __restrict__ outidx, float* __restrict__ counts,
    int* __restrict__ rescue_n, int* __restrict__ rescue_list, int N) {
  const int lane = threadIdx.x;
  const int rowbase = blockIdx.x * 64;
  const int row = rowbase + lane;

  // ascending slice order + strict > preserves first-occurrence argmin
  float b1c = out_b1[row];
  int bi = out_i1[row];
  float b2c = out_b2[row];
#pragma unroll
  for (int k = 1; k < ESLICES; ++k) {
    float sk = out_b1[(size_t)k * N + row];
    int ek = out_i1[(size_t)k * N + row];
    float qk = out_b2[(size_t)k * N + row];
    b2c = fmaxf(fmaxf(b2c, qk), fminf(sk, b1c));
    bool take = sk > b1c;
    b1c = take ? sk : b1c;
    bi = take ? ek : bi;
  }
  float gap2 = 2.0f * (b1c - b2c);

  outidx[row] = (float)bi;  // tentative for flagged rows; rescue overwrites
  if (gap2 < TAU) {
    int p = atomicAdd(rescue_n, 1);
    rescue_list[p] = row;
  } else {
    atomicAdd(&counts[bi], 1.0f);  // exact sums of 1.0f
  }
  for (int r = 0; r < 64; ++r) {
    int idx_r = __shfl(bi, r, 64);
    outq[(size_t)(rowbase + r) * D + lane] = dcb[(size_t)idx_r * D + lane];
  }
}

// ---------------- Kernel 4a: parallel exact rescue scan -----------------------
__global__ __launch_bounds__(64) void rescue_scan_kernel(
    const float* __restrict__ X, const float* __restrict__ dcb,
    const float* __restrict__ c2h, const int* __restrict__ rescue_n,
    const int* __restrict__ rescue_list,
    float* __restrict__ pd, int* __restrict__ pi) {
  const int lane = threadIdx.x;
  const int nu = (*rescue_n) * NSLICE;
  for (int u = blockIdx.x; u < nu; u += gridDim.x) {
    const int li = u >> 3;
    const int sl = u & (NSLICE - 1);
    const int row = rescue_list[li];

    const float4* xr = (const float4*)(X + (size_t)row * D);
    float4 x[16];
#pragma unroll
    for (int k = 0; k < 16; ++k) x[k] = xr[k];  // wave-uniform broadcast loads

    float best = 3.4e38f;
    int bidx = 0x7fffffff;
    const int e0 = sl * SLICE_E;
#pragma unroll 2
    for (int j = 0; j < SLICE_E / 64; ++j) {
      const int e = e0 + j * 64 + lane;  // ascending per lane -> strict < = first min
      const float4* cp = (const float4*)(dcb + (size_t)e * D);
      float d0 = 0.f, d1 = 0.f, d2 = 0.f, d3 = 0.f;
#pragma unroll
      for (int k = 0; k < 16; ++k) {
        float4 c = cp[k];
        d0 = fmaf(x[k].x, c.x, d0);
        d1 = fmaf(x[k].y, c.y, d1);
        d2 = fmaf(x[k].z, c.z, d2);
        d3 = fmaf(x[k].w, c.w, d3);
      }
      float d = c2h[e] - ((d0 + d1) + (d2 + d3));  // monotone in true distance
      if (d < best) { best = d; bidx = e; }
    }
#pragma unroll
    for (int m = 1; m < 64; m <<= 1) {
      float od = __shfl_xor(best, m, 64);
      int oi = __shfl_xor(bidx, m, 64);
      if (od < best || (od == best && oi < bidx)) { best = od; bidx = oi; }
    }
    if (lane == 0) { pd[u] = best; pi[u] = bidx; }
  }
}

// ---------------- Kernel 4b: rescue finalize ----------------------------------
__global__ __launch_bounds__(64) void rescue_fin_kernel(
    const float* __restrict__ dcb, const int* __restrict__ rescue_n,
    const int* __restrict__ rescue_list, const float* __restrict__ pd,
    const int* __restrict__ pi, float* __restrict__ outq,
    float* __restrict__ outidx, float* __restrict__ counts) {
  const int lane = threadIdx.x;
  const int nr = *rescue_n;
  for (int li = blockIdx.x; li < nr; li += gridDim.x) {
    const int row = rescue_list[li];
    float d = (lane < NSLICE) ? pd[li * NSLICE + lane] : 3.5e38f;
    int ix = (lane < NSLICE) ? pi[li * NSLICE + lane] : 0x7fffffff;
#pragma unroll
    for (int m = 1; m < NSLICE; m <<= 1) {
      float od = __shfl_xor(d, m, 64);
      int oi = __shfl_xor(ix, m, 64);
      if (od < d || (od == d && oi < ix)) { d = od; ix = oi; }
    }
    int bfin = __shfl(ix, 0, 64);
    if (lane == 0) {
      outidx[row] = (float)bfin;
      atomicAdd(&counts[bfin], 1.0f);
    }
    outq[(size_t)row * D + lane] = dcb[(size_t)bfin * D + lane];
  }
}

// ---------------- Kernel 5: perplexity ----------------------------------------
__global__ __launch_bounds__(256) void vq_perp_kernel(
    const float* __restrict__ counts, float* __restrict__ out, int E, float invN) {
  __shared__ float red[4];
  float s = 0.f;
  for (int j = threadIdx.x; j < E; j += 256) {
    float p = counts[j] * invN;
    s += p * logf(p + 1e-10f);
  }
#pragma unroll
  for (int off = 32; off > 0; off >>= 1) s += __shfl_down(s, off, 64);
  int wid = threadIdx.x >> 6;
  if ((threadIdx.x & 63) == 0) red[wid] = s;
  __syncthreads();
  if (threadIdx.x == 0) {
    float t = (red[0] + red[1]) + (red[2] + red[3]);
    out[0] = expf(-t);
  }
}

static inline size_t align256(size_t x) { return (x + 255) & ~(size_t)255; }

extern "C" void kernel_launch(void* const* d_in, const int* in_sizes, int n_in,
                              void* d_out, int out_size, void* d_ws, size_t ws_size,
                              hipStream_t stream) {
  const float* X      = (const float*)d_in[0];
  const float* cb     = (const float*)d_in[1];
  const float* dither = (const float*)d_in[2];

  const int N   = in_sizes[0] / D;  // 65536
  const int E   = in_sizes[1] / D;  // 4096
  const int Em1 = in_sizes[2];      // 4095

  char* w = (char*)d_ws;
  float* dcb            = (float*)w;          w += align256((size_t)E_PAD * D * sizeof(float));
  unsigned short* dcbh  = (unsigned short*)w; w += align256((size_t)E_PAD * D * sizeof(short));
  unsigned short* dcbl  = (unsigned short*)w; w += align256((size_t)E_PAD * D * sizeof(short));
  float* c2h            = (float*)w;          w += align256((size_t)E_PAD * sizeof(float));
  float* out_b1         = (float*)w;          w += align256((size_t)ESLICES * N * sizeof(float));
  int* out_i1           = (int*)w;            w += align256((size_t)ESLICES * N * sizeof(int));
  float* out_b2         = (float*)w;          w += align256((size_t)ESLICES * N * sizeof(float));
  float* counts         = (float*)w;          w += align256((size_t)E_PAD * sizeof(float));
  int* rescue_n         = (int*)w;            w += align256(sizeof(int));
  int* rescue_list      = (int*)w;            w += align256((size_t)N * sizeof(int));
  float* pd             = (float*)w;          w += align256((size_t)N * NSLICE * sizeof(float));
  int* pi               = (int*)w;            w += align256((size_t)N * NSLICE * sizeof(int));

  float* outq   = (float*)d_out;
  float* perp   = (float*)d_out + (size_t)N * D;
  float* outidx = (float*)d_out + (size_t)N * D + 1;

  build_kernel<<<E_PAD, 64, 0, stream>>>(cb, dither, dcb, dcbh, dcbl, c2h,
                                         counts, rescue_n, E, Em1);

  dim3 g2(N / 256, ESLICES);
  vq_mfma_kernel<<<g2, BLK, 0, stream>>>(X, dcbh, dcbl, c2h, out_b1, out_i1, out_b2, N);

  finish_kernel<<<N / 64, 64, 0, stream>>>(out_b1, out_i1, out_b2, dcb, outq, outidx,
                                           counts, rescue_n, rescue_list, N);

  rescue_scan_kernel<<<2048, 64, 0, stream>>>(X, dcb, c2h, rescue_n, rescue_list, pd, pi);

  rescue_fin_kernel<<<1024, 64, 0, stream>>>(dcb, rescue_n, rescue_list, pd, pi,
                                             outq, outidx, counts);

  vq_perp_kernel<<<1, 256, 0, stream>>>(counts, perp, E, 1.0f / (float)N);
}

// Round 13
// 166.259 us; speedup vs baseline: 1.1476x; 1.1476x over previous
//
#include <hip/hip_runtime.h>
#include <math.h>

// SpaceFillingVQ: N=65536 rows, D=64, E=4096 entries.
// bf16-split (3-term) MFMA distance pass, 32 rows/wave, E in 2 slices
// (16 waves/CU). Chunk body restructured into tile-PAIRS: 24-MFMA setprio
// cluster + deferred epilogue (T5 + phase-split). fp32 rescue for gap < TAU.

constexpr int D = 64;
constexpr int CHUNK = 64;           // codebook entries staged per iteration
constexpr int NTILES = CHUNK / 16;  // 4 MFMA tiles per chunk (2 pairs)
constexpr int E_PAD = 4096;
constexpr int ESLICES = 2;
constexpr int SLICE = E_PAD / ESLICES;  // 2048 entries per slice
constexpr int NCH = SLICE / CHUNK;      // 32 chunks per slice
constexpr float TAU = 0.01f;
constexpr int NSLICE = 8;
constexpr int SLICE_E = E_PAD / NSLICE;
constexpr int BLK = 256;            // 4 waves; each wave owns 32 rows

typedef __attribute__((ext_vector_type(8))) short bf16x8;
typedef __attribute__((ext_vector_type(4))) float f32x4;

__device__ inline unsigned short f2bf(float x) {  // round-to-nearest-even bf16
  unsigned int u = __float_as_uint(x);
  u = (u + 0x7fffu + ((u >> 16) & 1u)) >> 16;
  return (unsigned short)u;
}
__device__ inline float bf2f(unsigned short h) {
  return __uint_as_float(((unsigned int)h) << 16);
}

__device__ __forceinline__ void gll16(const void* g, void* l) {
  __builtin_amdgcn_global_load_lds(
      (const __attribute__((address_space(1))) unsigned int*)g,
      (__attribute__((address_space(3))) unsigned int*)l, 16, 0, 0);
}
__device__ __forceinline__ void gll4(const void* g, void* l) {
  __builtin_amdgcn_global_load_lds(
      (const __attribute__((address_space(1))) unsigned int*)g,
      (__attribute__((address_space(3))) unsigned int*)l, 4, 0, 0);
}

// ---------------- Kernel 1: dithered codebook (f32 + bf16 hi/lo split) + c2/2 ----
__global__ __launch_bounds__(64) void build_kernel(
    const float* __restrict__ cb, const float* __restrict__ dither,
    float* __restrict__ dcb, unsigned short* __restrict__ dcbh,
    unsigned short* __restrict__ dcbl, float* __restrict__ c2h,
    float* __restrict__ counts, int* __restrict__ rescue_n, int E, int Em1) {
  int i = blockIdx.x;
  int k = threadIdx.x;
  if (k == 0) counts[i] = 0.0f;
  if (i == 0 && k == 1) *rescue_n = 0;
  if (i >= Em1) {  // pad entries: never selectable
    dcb[(size_t)i * D + k] = 0.f;
    dcbh[(size_t)i * D + k] = 0;
    dcbl[(size_t)i * D + k] = 0;
    if (k == 0) c2h[i] = 3.0e38f;
    return;
  }
  float frac = dither[i] + (float)i;  // replicate reference f32 arithmetic
  int ii = (int)floorf(frac);
  ii = max(0, min(ii, E - 2));
  float r = frac - (float)ii;
  float v = (1.0f - r) * cb[(size_t)ii * D + k] + r * cb[(size_t)(ii + 1) * D + k];
  dcb[(size_t)i * D + k] = v;
  unsigned short h = f2bf(v);
  unsigned short l = f2bf(v - bf2f(h));
  dcbh[(size_t)i * D + k] = h;
  dcbl[(size_t)i * D + k] = l;
  float s = v * v;
#pragma unroll
  for (int off = 32; off > 0; off >>= 1) s += __shfl_down(s, off, 64);
  if (k == 0) c2h[i] = 0.5f * s;
}

// ---------------- Kernel 2: MFMA distance over one E-slice --------------------
// grid (N/128, 2); block 256 = 4 waves; 32 rows/wave (2 row-groups).
// Per chunk: 2 tile-pairs; each pair = B-reads -> 24-MFMA setprio cluster ->
// deferred epilogue. Double-buffered global_load_lds staging.
__global__ __launch_bounds__(BLK, 4) void vq_mfma_kernel(
    const float* __restrict__ X, const unsigned short* __restrict__ dcbh,
    const unsigned short* __restrict__ dcbl, const float* __restrict__ c2h,
    float* __restrict__ out_b1, int* __restrict__ out_i1,
    float* __restrict__ out_b2, int N) {
  __shared__ unsigned short s_h[2][CHUNK * D];
  __shared__ unsigned short s_l[2][CHUNK * D];
  __shared__ float s_c2[2][CHUNK];

  const int tid = threadIdx.x;
  const int lane = tid & 63;
  const int wv = tid >> 6;
  const int col = lane & 15;   // MFMA col / A-row within 16
  const int kg = lane >> 4;    // k-group 0..3
  const int slice = blockIdx.y;
  const int sbase = slice * SLICE;
  const int wvbase = blockIdx.x * 128 + wv * 32;

  // ---- A fragments for 2 row-groups: bf16 hi/lo, 2 K-halves (k 0-31, 32-63)
  bf16x8 ah0[2], ah1[2], al0[2], al1[2];
#pragma unroll
  for (int rg = 0; rg < 2; ++rg) {
    const float* xp = X + (size_t)(wvbase + rg * 16 + col) * D + kg * 8;
#pragma unroll
    for (int i = 0; i < 8; ++i) {
      float x0 = xp[i], x1 = xp[32 + i];
      unsigned short h0 = f2bf(x0), h1 = f2bf(x1);
      ah0[rg][i] = (short)h0; ah1[rg][i] = (short)h1;
      al0[rg][i] = (short)f2bf(x0 - bf2f(h0));
      al1[rg][i] = (short)f2bf(x1 - bf2f(h1));
    }
  }

  float b1[2][4], b2[2][4];
  int i1[2][4];
#pragma unroll
  for (int rg = 0; rg < 2; ++rg)
#pragma unroll
    for (int r = 0; r < 4; ++r) { b1[rg][r] = -3.4e38f; b2[rg][r] = -3.4e38f; i1[rg][r] = sbase; }

  const int xs = col & 7;  // XOR-swizzle key (entry&7 within tile == col&7)

  // staging: pre-swizzled GLOBAL source + linear LDS dest (rule #21).
  auto stage = [&](int ch, int buf) {
#pragma unroll
    for (int i = 0; i < 2; ++i) {
      const int u = (wv * 2 + i) * 64 + lane;
      const int e = u >> 3, g = u & 7;
      const size_t goff = (((size_t)(sbase + ch * CHUNK + e)) << 6) + ((g ^ (e & 7)) << 3);
      char* dst_h = (char*)s_h[buf] + (size_t)(wv * 2 + i) * 1024;  // +lane*16 by HW
      char* dst_l = (char*)s_l[buf] + (size_t)(wv * 2 + i) * 1024;
      gll16(dcbh + goff, dst_h);
      gll16(dcbl + goff, dst_l);
    }
    if (wv == 0) {  // wave-uniform branch; 64 floats
      gll4(c2h + sbase + ch * CHUNK + lane, (char*)s_c2[buf]);
    }
  };

  stage(0, 0);
  __syncthreads();  // drains vmcnt -> buf0 valid
  int cur = 0;

  for (int ch = 0; ch < NCH; ++ch) {
    const int ebase = sbase + ch * CHUNK;
    if (ch + 1 < NCH) stage(ch + 1, cur ^ 1);  // prefetch hides under MFMA below

#pragma unroll
    for (int p = 0; p < 2; ++p) {  // tile pairs {0,1}, {2,3}
      // ---- B-fragment reads for both tiles of the pair (8 ds_read_b128)
      bf16x8 Bh0[2], Bh1[2], Bl0[2], Bl1[2];
      float hc2[2];
#pragma unroll
      for (int q = 0; q < 2; ++q) {
        const int el = (p * 2 + q) * 16 + col;
        const char* bb = (const char*)s_h[cur] + el * 128;
        const char* ll = (const char*)s_l[cur] + el * 128;
        Bh0[q] = *(const bf16x8*)(bb + ((kg ^ xs) << 4));
        Bh1[q] = *(const bf16x8*)(bb + (((kg + 4) ^ xs) << 4));
        Bl0[q] = *(const bf16x8*)(ll + ((kg ^ xs) << 4));
        Bl1[q] = *(const bf16x8*)(ll + (((kg + 4) ^ xs) << 4));
        hc2[q] = s_c2[cur][el];
      }
      // ---- 24-MFMA cluster (4 independent 6-chains), setprio-wrapped
      f32x4 acc[2][2];
#pragma unroll
      for (int q = 0; q < 2; ++q)
#pragma unroll
        for (int rg = 0; rg < 2; ++rg)
          acc[q][rg] = {-hc2[q], -hc2[q], -hc2[q], -hc2[q]};  // s = acc directly
      __builtin_amdgcn_s_setprio(1);
#pragma unroll
      for (int q = 0; q < 2; ++q)
#pragma unroll
        for (int rg = 0; rg < 2; ++rg) {
          acc[q][rg] = __builtin_amdgcn_mfma_f32_16x16x32_bf16(ah0[rg], Bh0[q], acc[q][rg], 0, 0, 0);
          acc[q][rg] = __builtin_amdgcn_mfma_f32_16x16x32_bf16(ah1[rg], Bh1[q], acc[q][rg], 0, 0, 0);
          acc[q][rg] = __builtin_amdgcn_mfma_f32_16x16x32_bf16(ah0[rg], Bl0[q], acc[q][rg], 0, 0, 0);
          acc[q][rg] = __builtin_amdgcn_mfma_f32_16x16x32_bf16(ah1[rg], Bl1[q], acc[q][rg], 0, 0, 0);
          acc[q][rg] = __builtin_amdgcn_mfma_f32_16x16x32_bf16(al0[rg], Bh0[q], acc[q][rg], 0, 0, 0);
          acc[q][rg] = __builtin_amdgcn_mfma_f32_16x16x32_bf16(al1[rg], Bh1[q], acc[q][rg], 0, 0, 0);
        }
      __builtin_amdgcn_s_setprio(0);
      // ---- deferred epilogue for the pair (ascending entry order kept)
#pragma unroll
      for (int q = 0; q < 2; ++q) {
        const int colg = ebase + (p * 2 + q) * 16 + col;
#pragma unroll
        for (int rg = 0; rg < 2; ++rg)
#pragma unroll
          for (int r = 0; r < 4; ++r) {
            float s = acc[q][rg][r];
            bool gt = s > b1[rg][r];  // strict > -> first occurrence
            b2[rg][r] = __builtin_amdgcn_fmed3f(b2[rg][r], s, b1[rg][r]);  // b2<=b1
            b1[rg][r] = fmaxf(b1[rg][r], s);
            i1[rg][r] = gt ? colg : i1[rg][r];
          }
      }
    }

    __syncthreads();  // drains vmcnt(0): prefetch landed; lgkm: reads done
    cur ^= 1;
  }

  // cross-lane reduce over 16 cols (xor within lane&15; same row group = lane>>4)
#pragma unroll
  for (int m = 1; m < 16; m <<= 1) {
#pragma unroll
    for (int rg = 0; rg < 2; ++rg)
#pragma unroll
      for (int r = 0; r < 4; ++r) {
        float ob1 = __shfl_xor(b1[rg][r], m, 64);
        float ob2 = __shfl_xor(b2[rg][r], m, 64);
        int oi1 = __shfl_xor(i1[rg][r], m, 64);
        float loser = fminf(b1[rg][r], ob1);
        b2[rg][r] = fmaxf(fmaxf(b2[rg][r], ob2), loser);
        bool take = (ob1 > b1[rg][r]) || (ob1 == b1[rg][r] && oi1 < i1[rg][r]);
        b1[rg][r] = take ? ob1 : b1[rg][r];
        i1[rg][r] = take ? oi1 : i1[rg][r];
      }
  }
  if (col == 0) {
#pragma unroll
    for (int rg = 0; rg < 2; ++rg)
#pragma unroll
      for (int r = 0; r < 4; ++r) {
        int row = wvbase + rg * 16 + kg * 4 + r;  // row=(lane>>4)*4+reg (C/D map)
        size_t o = (size_t)slice * N + row;
        out_b1[o] = b1[rg][r];
        out_i1[o] = i1[rg][r];
        out_b2[o] = b2[rg][r];
      }
  }
}

// ---------------- Kernel 3: merge slices, histogram, quantized gather --------
// 256 threads = 4 waves; each wave finalizes 64 rows.
__global__ __launch_bounds__(256) void finish_kernel(
    const float* __restrict__ out_b1, const int* __restrict__ out_i1,
    const float* __restrict__ out_b2,
    const float* __restrict__ dcb, float* __restrict__ outq,
    float* __restrict__ outidx, float* __restrict__ counts,
    int* __restrict__ rescue_n, int* __restrict__ rescue_list, int N) {
  const int lane = threadIdx.x & 63;
  const int wv = threadIdx.x >> 6;
  const int rowbase = blockIdx.x * 256 + wv * 64;
  const int row = rowbase + lane;

  // ascending slice order + strict > preserves first-occurrence argmin
  float b1c = out_b1[row];
  int bi = out_i1[row];
  float b2c = out_b2[row];
#pragma unroll
  for (int k = 1; k < ESLICES; ++k) {
    float sk = out_b1[(size_t)k * N + row];
    int ek = out_i1[(size_t)k * N + row];
    float qk = out_b2[(size_t)k * N + row];
    b2c = fmaxf(fmaxf(b2c, qk), fminf(sk, b1c));
    bool take = sk > b1c;
    b1c = take ? sk : b1c;
    bi = take ? ek : bi;
  }
  float gap2 = 2.0f * (b1c - b2c);

  outidx[row] = (float)bi;  // tentative for flagged rows; rescue overwrites
  if (gap2 < TAU) {
    int p = atomicAdd(rescue_n, 1);
    rescue_list[p] = row;
  } else {
    atomicAdd(&counts[bi], 1.0f);  // exact sums of 1.0f
  }
  for (int r = 0; r < 64; ++r) {
    int idx_r = __shfl(bi, r, 64);
    outq[(size_t)(rowbase + r) * D + lane] = dcb[(size_t)idx_r * D + lane];
  }
}

// ---------------- Kernel 4a: parallel exact rescue scan -----------------------
__global__ __launch_bounds__(64) void rescue_scan_kernel(
    const float* __restrict__ X, const float* __restrict__ dcb,
    const float* __restrict__ c2h, const int* __restrict__ rescue_n,
    const int* __restrict__ rescue_list,
    float* __restrict__ pd, int* __restrict__ pi) {
  const int lane = threadIdx.x;
  const int nu = (*rescue_n) * NSLICE;
  for (int u = blockIdx.x; u < nu; u += gridDim.x) {
    const int li = u >> 3;
    const int sl = u & (NSLICE - 1);
    const int row = rescue_list[li];

    const float4* xr = (const float4*)(X + (size_t)row * D);
    float4 x[16];
#pragma unroll
    for (int k = 0; k < 16; ++k) x[k] = xr[k];  // wave-uniform broadcast loads

    float best = 3.4e38f;
    int bidx = 0x7fffffff;
    const int e0 = sl * SLICE_E;
#pragma unroll 2
    for (int j = 0; j < SLICE_E / 64; ++j) {
      const int e = e0 + j * 64 + lane;  // ascending per lane -> strict < = first min
      const float4* cp = (const float4*)(dcb + (size_t)e * D);
      float d0 = 0.f, d1 = 0.f, d2 = 0.f, d3 = 0.f;
#pragma unroll
      for (int k = 0; k < 16; ++k) {
        float4 c = cp[k];
        d0 = fmaf(x[k].x, c.x, d0);
        d1 = fmaf(x[k].y, c.y, d1);
        d2 = fmaf(x[k].z, c.z, d2);
        d3 = fmaf(x[k].w, c.w, d3);
      }
      float d = c2h[e] - ((d0 + d1) + (d2 + d3));  // monotone in true distance
      if (d < best) { best = d; bidx = e; }
    }
#pragma unroll
    for (int m = 1; m < 64; m <<= 1) {
      float od = __shfl_xor(best, m, 64);
      int oi = __shfl_xor(bidx, m, 64);
      if (od < best || (od == best && oi < bidx)) { best = od; bidx = oi; }
    }
    if (lane == 0) { pd[u] = best; pi[u] = bidx; }
  }
}

// ---------------- Kernel 4b: rescue finalize ----------------------------------
__global__ __launch_bounds__(64) void rescue_fin_kernel(
    const float* __restrict__ dcb, const int* __restrict__ rescue_n,
    const int* __restrict__ rescue_list, const float* __restrict__ pd,
    const int* __restrict__ pi, float* __restrict__ outq,
    float* __restrict__ outidx, float* __restrict__ counts) {
  const int lane = threadIdx.x;
  const int nr = *rescue_n;
  for (int li = blockIdx.x; li < nr; li += gridDim.x) {
    const int row = rescue_list[li];
    float d = (lane < NSLICE) ? pd[li * NSLICE + lane] : 3.5e38f;
    int ix = (lane < NSLICE) ? pi[li * NSLICE + lane] : 0x7fffffff;
#pragma unroll
    for (int m = 1; m < NSLICE; m <<= 1) {
      float od = __shfl_xor(d, m, 64);
      int oi = __shfl_xor(ix, m, 64);
      if (od < d || (od == d && oi < ix)) { d = od; ix = oi; }
    }
    int bfin = __shfl(ix, 0, 64);
    if (lane == 0) {
      outidx[row] = (float)bfin;
      atomicAdd(&counts[bfin], 1.0f);
    }
    outq[(size_t)row * D + lane] = dcb[(size_t)bfin * D + lane];
  }
}

// ---------------- Kernel 5: perplexity ----------------------------------------
__global__ __launch_bounds__(256) void vq_perp_kernel(
    const float* __restrict__ counts, float* __restrict__ out, int E, float invN) {
  __shared__ float red[4];
  float s = 0.f;
  for (int j = threadIdx.x; j < E; j += 256) {
    float p = counts[j] * invN;
    s += p * logf(p + 1e-10f);
  }
#pragma unroll
  for (int off = 32; off > 0; off >>= 1) s += __shfl_down(s, off, 64);
  int wid = threadIdx.x >> 6;
  if ((threadIdx.x & 63) == 0) red[wid] = s;
  __syncthreads();
  if (threadIdx.x == 0) {
    float t = (red[0] + red[1]) + (red[2] + red[3]);
    out[0] = expf(-t);
  }
}

static inline size_t align256(size_t x) { return (x + 255) & ~(size_t)255; }

extern "C" void kernel_launch(void* const* d_in, const int* in_sizes, int n_in,
                              void* d_out, int out_size, void* d_ws, size_t ws_size,
                              hipStream_t stream) {
  const float* X      = (const float*)d_in[0];
  const float* cb     = (const float*)d_in[1];
  const float* dither = (const float*)d_in[2];

  const int N   = in_sizes[0] / D;  // 65536
  const int E   = in_sizes[1] / D;  // 4096
  const int Em1 = in_sizes[2];      // 4095

  char* w = (char*)d_ws;
  float* dcb            = (float*)w;          w += align256((size_t)E_PAD * D * sizeof(float));
  unsigned short* dcbh  = (unsigned short*)w; w += align256((size_t)E_PAD * D * sizeof(short));
  unsigned short* dcbl  = (unsigned short*)w; w += align256((size_t)E_PAD * D * sizeof(short));
  float* c2h            = (float*)w;          w += align256((size_t)E_PAD * sizeof(float));
  float* out_b1         = (float*)w;          w += align256((size_t)ESLICES * N * sizeof(float));
  int* out_i1           = (int*)w;            w += align256((size_t)ESLICES * N * sizeof(int));
  float* out_b2         = (float*)w;          w += align256((size_t)ESLICES * N * sizeof(float));
  float* counts         = (float*)w;          w += align256((size_t)E_PAD * sizeof(float));
  int* rescue_n         = (int*)w;            w += align256(sizeof(int));
  int* rescue_list      = (int*)w;            w += align256((size_t)N * sizeof(int));
  float* pd             = (float*)w;          w += align256((size_t)N * NSLICE * sizeof(float));
  int* pi               = (int*)w;            w += align256((size_t)N * NSLICE * sizeof(int));

  float* outq   = (float*)d_out;
  float* perp   = (float*)d_out + (size_t)N * D;
  float* outidx = (float*)d_out + (size_t)N * D + 1;

  build_kernel<<<E_PAD, 64, 0, stream>>>(cb, dither, dcb, dcbh, dcbl, c2h,
                                         counts, rescue_n, E, Em1);

  dim3 g2(N / 128, ESLICES);
  vq_mfma_kernel<<<g2, BLK, 0, stream>>>(X, dcbh, dcbl, c2h, out_b1, out_i1, out_b2, N);

  finish_kernel<<<N / 256, 256, 0, stream>>>(out_b1, out_i1, out_b2, dcb, outq, outidx,
                                             counts, rescue_n, rescue_list, N);

  rescue_scan_kernel<<<2048, 64, 0, stream>>>(X, dcb, c2h, rescue_n, rescue_list, pd, pi);

  rescue_fin_kernel<<<1024, 64, 0, stream>>>(dcb, rescue_n, rescue_list, pd, pi,
                                             outq, outidx, counts);

  vq_perp_kernel<<<1, 256, 0, stream>>>(counts, perp, E, 1.0f / (float)N);
}

// Round 14
// 165.359 us; speedup vs baseline: 1.1539x; 1.0054x over previous
//
#include <hip/hip_runtime.h>
#include <math.h>

// SpaceFillingVQ: N=65536 rows, D=64, E=4096 entries.
// bf16-split (3-term) MFMA distance pass (r13 structure, plateau-verified at
// ~117us = m97-class 2-barrier structural ceiling). This round: aux-kernel
// efficiency (finish float4 gather, build consolidation). Rescue gap < TAU.

constexpr int D = 64;
constexpr int CHUNK = 64;           // codebook entries staged per iteration
constexpr int NTILES = CHUNK / 16;  // 4 MFMA tiles per chunk (2 pairs)
constexpr int E_PAD = 4096;
constexpr int ESLICES = 2;
constexpr int SLICE = E_PAD / ESLICES;  // 2048 entries per slice
constexpr int NCH = SLICE / CHUNK;      // 32 chunks per slice
constexpr float TAU = 0.01f;
constexpr int NSLICE = 8;
constexpr int SLICE_E = E_PAD / NSLICE;
constexpr int BLK = 256;            // 4 waves; each wave owns 32 rows

typedef __attribute__((ext_vector_type(8))) short bf16x8;
typedef __attribute__((ext_vector_type(4))) float f32x4;

__device__ inline unsigned short f2bf(float x) {  // round-to-nearest-even bf16
  unsigned int u = __float_as_uint(x);
  u = (u + 0x7fffu + ((u >> 16) & 1u)) >> 16;
  return (unsigned short)u;
}
__device__ inline float bf2f(unsigned short h) {
  return __uint_as_float(((unsigned int)h) << 16);
}

__device__ __forceinline__ void gll16(const void* g, void* l) {
  __builtin_amdgcn_global_load_lds(
      (const __attribute__((address_space(1))) unsigned int*)g,
      (__attribute__((address_space(3))) unsigned int*)l, 16, 0, 0);
}
__device__ __forceinline__ void gll4(const void* g, void* l) {
  __builtin_amdgcn_global_load_lds(
      (const __attribute__((address_space(1))) unsigned int*)g,
      (__attribute__((address_space(3))) unsigned int*)l, 4, 0, 0);
}

// ---------------- Kernel 1: dithered codebook (f32 + bf16 hi/lo split) + c2/2 ----
// 256-thread blocks, 4 entries/block (one per wave). Also zeroes counts/rescue_n.
__global__ __launch_bounds__(256) void build_kernel(
    const float* __restrict__ cb, const float* __restrict__ dither,
    float* __restrict__ dcb, unsigned short* __restrict__ dcbh,
    unsigned short* __restrict__ dcbl, float* __restrict__ c2h,
    float* __restrict__ counts, int* __restrict__ rescue_n, int E, int Em1) {
  int i = blockIdx.x * 4 + (threadIdx.x >> 6);
  int k = threadIdx.x & 63;
  if (k == 0) counts[i] = 0.0f;
  if (i == 0 && k == 1) *rescue_n = 0;
  if (i >= Em1) {  // pad entries: never selectable
    dcb[(size_t)i * D + k] = 0.f;
    dcbh[(size_t)i * D + k] = 0;
    dcbl[(size_t)i * D + k] = 0;
    if (k == 0) c2h[i] = 3.0e38f;
    return;
  }
  float frac = dither[i] + (float)i;  // replicate reference f32 arithmetic
  int ii = (int)floorf(frac);
  ii = max(0, min(ii, E - 2));
  float r = frac - (float)ii;
  float v = (1.0f - r) * cb[(size_t)ii * D + k] + r * cb[(size_t)(ii + 1) * D + k];
  dcb[(size_t)i * D + k] = v;
  unsigned short h = f2bf(v);
  unsigned short l = f2bf(v - bf2f(h));
  dcbh[(size_t)i * D + k] = h;
  dcbl[(size_t)i * D + k] = l;
  float s = v * v;
#pragma unroll
  for (int off = 32; off > 0; off >>= 1) s += __shfl_down(s, off, 64);
  if (k == 0) c2h[i] = 0.5f * s;
}

// ---------------- Kernel 2: MFMA distance over one E-slice (r13, unchanged) ---
__global__ __launch_bounds__(BLK, 4) void vq_mfma_kernel(
    const float* __restrict__ X, const unsigned short* __restrict__ dcbh,
    const unsigned short* __restrict__ dcbl, const float* __restrict__ c2h,
    float* __restrict__ out_b1, int* __restrict__ out_i1,
    float* __restrict__ out_b2, int N) {
  __shared__ unsigned short s_h[2][CHUNK * D];
  __shared__ unsigned short s_l[2][CHUNK * D];
  __shared__ float s_c2[2][CHUNK];

  const int tid = threadIdx.x;
  const int lane = tid & 63;
  const int wv = tid >> 6;
  const int col = lane & 15;   // MFMA col / A-row within 16
  const int kg = lane >> 4;    // k-group 0..3
  const int slice = blockIdx.y;
  const int sbase = slice * SLICE;
  const int wvbase = blockIdx.x * 128 + wv * 32;

  // ---- A fragments for 2 row-groups: bf16 hi/lo, 2 K-halves (k 0-31, 32-63)
  bf16x8 ah0[2], ah1[2], al0[2], al1[2];
#pragma unroll
  for (int rg = 0; rg < 2; ++rg) {
    const float* xp = X + (size_t)(wvbase + rg * 16 + col) * D + kg * 8;
#pragma unroll
    for (int i = 0; i < 8; ++i) {
      float x0 = xp[i], x1 = xp[32 + i];
      unsigned short h0 = f2bf(x0), h1 = f2bf(x1);
      ah0[rg][i] = (short)h0; ah1[rg][i] = (short)h1;
      al0[rg][i] = (short)f2bf(x0 - bf2f(h0));
      al1[rg][i] = (short)f2bf(x1 - bf2f(h1));
    }
  }

  float b1[2][4], b2[2][4];
  int i1[2][4];
#pragma unroll
  for (int rg = 0; rg < 2; ++rg)
#pragma unroll
    for (int r = 0; r < 4; ++r) { b1[rg][r] = -3.4e38f; b2[rg][r] = -3.4e38f; i1[rg][r] = sbase; }

  const int xs = col & 7;  // XOR-swizzle key (entry&7 within tile == col&7)

  // staging: pre-swizzled GLOBAL source + linear LDS dest (rule #21).
  auto stage = [&](int ch, int buf) {
#pragma unroll
    for (int i = 0; i < 2; ++i) {
      const int u = (wv * 2 + i) * 64 + lane;
      const int e = u >> 3, g = u & 7;
      const size_t goff = (((size_t)(sbase + ch * CHUNK + e)) << 6) + ((g ^ (e & 7)) << 3);
      char* dst_h = (char*)s_h[buf] + (size_t)(wv * 2 + i) * 1024;  // +lane*16 by HW
      char* dst_l = (char*)s_l[buf] + (size_t)(wv * 2 + i) * 1024;
      gll16(dcbh + goff, dst_h);
      gll16(dcbl + goff, dst_l);
    }
    if (wv == 0) {  // wave-uniform branch; 64 floats
      gll4(c2h + sbase + ch * CHUNK + lane, (char*)s_c2[buf]);
    }
  };

  stage(0, 0);
  __syncthreads();  // drains vmcnt -> buf0 valid
  int cur = 0;

  for (int ch = 0; ch < NCH; ++ch) {
    const int ebase = sbase + ch * CHUNK;
    if (ch + 1 < NCH) stage(ch + 1, cur ^ 1);  // prefetch hides under MFMA below

#pragma unroll
    for (int p = 0; p < 2; ++p) {  // tile pairs {0,1}, {2,3}
      bf16x8 Bh0[2], Bh1[2], Bl0[2], Bl1[2];
      float hc2[2];
#pragma unroll
      for (int q = 0; q < 2; ++q) {
        const int el = (p * 2 + q) * 16 + col;
        const char* bb = (const char*)s_h[cur] + el * 128;
        const char* ll = (const char*)s_l[cur] + el * 128;
        Bh0[q] = *(const bf16x8*)(bb + ((kg ^ xs) << 4));
        Bh1[q] = *(const bf16x8*)(bb + (((kg + 4) ^ xs) << 4));
        Bl0[q] = *(const bf16x8*)(ll + ((kg ^ xs) << 4));
        Bl1[q] = *(const bf16x8*)(ll + (((kg + 4) ^ xs) << 4));
        hc2[q] = s_c2[cur][el];
      }
      f32x4 acc[2][2];
#pragma unroll
      for (int q = 0; q < 2; ++q)
#pragma unroll
        for (int rg = 0; rg < 2; ++rg)
          acc[q][rg] = {-hc2[q], -hc2[q], -hc2[q], -hc2[q]};  // s = acc directly
      __builtin_amdgcn_s_setprio(1);
#pragma unroll
      for (int q = 0; q < 2; ++q)
#pragma unroll
        for (int rg = 0; rg < 2; ++rg) {
          acc[q][rg] = __builtin_amdgcn_mfma_f32_16x16x32_bf16(ah0[rg], Bh0[q], acc[q][rg], 0, 0, 0);
          acc[q][rg] = __builtin_amdgcn_mfma_f32_16x16x32_bf16(ah1[rg], Bh1[q], acc[q][rg], 0, 0, 0);
          acc[q][rg] = __builtin_amdgcn_mfma_f32_16x16x32_bf16(ah0[rg], Bl0[q], acc[q][rg], 0, 0, 0);
          acc[q][rg] = __builtin_amdgcn_mfma_f32_16x16x32_bf16(ah1[rg], Bl1[q], acc[q][rg], 0, 0, 0);
          acc[q][rg] = __builtin_amdgcn_mfma_f32_16x16x32_bf16(al0[rg], Bh0[q], acc[q][rg], 0, 0, 0);
          acc[q][rg] = __builtin_amdgcn_mfma_f32_16x16x32_bf16(al1[rg], Bh1[q], acc[q][rg], 0, 0, 0);
        }
      __builtin_amdgcn_s_setprio(0);
#pragma unroll
      for (int q = 0; q < 2; ++q) {
        const int colg = ebase + (p * 2 + q) * 16 + col;
#pragma unroll
        for (int rg = 0; rg < 2; ++rg)
#pragma unroll
          for (int r = 0; r < 4; ++r) {
            float s = acc[q][rg][r];
            bool gt = s > b1[rg][r];  // strict > -> first occurrence
            b2[rg][r] = __builtin_amdgcn_fmed3f(b2[rg][r], s, b1[rg][r]);  // b2<=b1
            b1[rg][r] = fmaxf(b1[rg][r], s);
            i1[rg][r] = gt ? colg : i1[rg][r];
          }
      }
    }

    __syncthreads();  // drains vmcnt(0): prefetch landed; lgkm: reads done
    cur ^= 1;
  }

  // cross-lane reduce over 16 cols (xor within lane&15; same row group = lane>>4)
#pragma unroll
  for (int m = 1; m < 16; m <<= 1) {
#pragma unroll
    for (int rg = 0; rg < 2; ++rg)
#pragma unroll
      for (int r = 0; r < 4; ++r) {
        float ob1 = __shfl_xor(b1[rg][r], m, 64);
        float ob2 = __shfl_xor(b2[rg][r], m, 64);
        int oi1 = __shfl_xor(i1[rg][r], m, 64);
        float loser = fminf(b1[rg][r], ob1);
        b2[rg][r] = fmaxf(fmaxf(b2[rg][r], ob2), loser);
        bool take = (ob1 > b1[rg][r]) || (ob1 == b1[rg][r] && oi1 < i1[rg][r]);
        b1[rg][r] = take ? ob1 : b1[rg][r];
        i1[rg][r] = take ? oi1 : i1[rg][r];
      }
  }
  if (col == 0) {
#pragma unroll
    for (int rg = 0; rg < 2; ++rg)
#pragma unroll
      for (int r = 0; r < 4; ++r) {
        int row = wvbase + rg * 16 + kg * 4 + r;  // row=(lane>>4)*4+reg (C/D map)
        size_t o = (size_t)slice * N + row;
        out_b1[o] = b1[rg][r];
        out_i1[o] = i1[rg][r];
        out_b2[o] = b2[rg][r];
      }
  }
}

// ---------------- Kernel 3: merge slices, histogram, float4 gather ------------
// 64 threads (1 wave) per block, 64 rows; gather via LDS idx + float4 lanes.
__global__ __launch_bounds__(64) void finish_kernel(
    const float* __restrict__ out_b1, const int* __restrict__ out_i1,
    const float* __restrict__ out_b2,
    const float* __restrict__ dcb, float* __restrict__ outq,
    float* __restrict__ outidx, float* __restrict__ counts,
    int* __restrict__ rescue_n, int* __restrict__ rescue_list, int N) {
  __shared__ int s_idx[64];
  const int lane = threadIdx.x;
  const int rowbase = blockIdx.x * 64;
  const int row = rowbase + lane;

  // ascending slice order + strict > preserves first-occurrence argmin
  float b1c = out_b1[row];
  int bi = out_i1[row];
  float b2c = out_b2[row];
#pragma unroll
  for (int k = 1; k < ESLICES; ++k) {
    float sk = out_b1[(size_t)k * N + row];
    int ek = out_i1[(size_t)k * N + row];
    float qk = out_b2[(size_t)k * N + row];
    b2c = fmaxf(fmaxf(b2c, qk), fminf(sk, b1c));
    bool take = sk > b1c;
    b1c = take ? sk : b1c;
    bi = take ? ek : bi;
  }
  float gap2 = 2.0f * (b1c - b2c);

  outidx[row] = (float)bi;  // tentative for flagged rows; rescue overwrites
  s_idx[lane] = bi;
  if (gap2 < TAU) {
    int p = atomicAdd(rescue_n, 1);
    rescue_list[p] = row;
  } else {
    atomicAdd(&counts[bi], 1.0f);  // exact sums of 1.0f
  }
  __syncthreads();

  // float4 gather: 16 iterations, 4 rows x 16 lanes each, 1KB contiguous stores
  const float4* dcb4 = (const float4*)dcb;
  float4* outq4 = (float4*)outq;
  const int rl = lane >> 4;      // row within quad
  const int c4 = lane & 15;      // float4 column
#pragma unroll 4
  for (int t = 0; t < 16; ++t) {
    const int rloc = t * 4 + rl;
    const int idx = s_idx[rloc];
    outq4[(size_t)(rowbase + rloc) * 16 + c4] = dcb4[(size_t)idx * 16 + c4];
  }
}

// ---------------- Kernel 4a: parallel exact rescue scan -----------------------
__global__ __launch_bounds__(64) void rescue_scan_kernel(
    const float* __restrict__ X, const float* __restrict__ dcb,
    const float* __restrict__ c2h, const int* __restrict__ rescue_n,
    const int* __restrict__ rescue_list,
    float* __restrict__ pd, int* __restrict__ pi) {
  const int lane = threadIdx.x;
  const int nu = (*rescue_n) * NSLICE;
  for (int u = blockIdx.x; u < nu; u += gridDim.x) {
    const int li = u >> 3;
    const int sl = u & (NSLICE - 1);
    const int row = rescue_list[li];

    const float4* xr = (const float4*)(X + (size_t)row * D);
    float4 x[16];
#pragma unroll
    for (int k = 0; k < 16; ++k) x[k] = xr[k];  // wave-uniform broadcast loads

    float best = 3.4e38f;
    int bidx = 0x7fffffff;
    const int e0 = sl * SLICE_E;
#pragma unroll 2
    for (int j = 0; j < SLICE_E / 64; ++j) {
      const int e = e0 + j * 64 + lane;  // ascending per lane -> strict < = first min
      const float4* cp = (const float4*)(dcb + (size_t)e * D);
      float d0 = 0.f, d1 = 0.f, d2 = 0.f, d3 = 0.f;
#pragma unroll
      for (int k = 0; k < 16; ++k) {
        float4 c = cp[k];
        d0 = fmaf(x[k].x, c.x, d0);
        d1 = fmaf(x[k].y, c.y, d1);
        d2 = fmaf(x[k].z, c.z, d2);
        d3 = fmaf(x[k].w, c.w, d3);
      }
      float d = c2h[e] - ((d0 + d1) + (d2 + d3));  // monotone in true distance
      if (d < best) { best = d; bidx = e; }
    }
#pragma unroll
    for (int m = 1; m < 64; m <<= 1) {
      float od = __shfl_xor(best, m, 64);
      int oi = __shfl_xor(bidx, m, 64);
      if (od < best || (od == best && oi < bidx)) { best = od; bidx = oi; }
    }
    if (lane == 0) { pd[u] = best; pi[u] = bidx; }
  }
}

// ---------------- Kernel 4b: rescue finalize ----------------------------------
__global__ __launch_bounds__(64) void rescue_fin_kernel(
    const float* __restrict__ dcb, const int* __restrict__ rescue_n,
    const int* __restrict__ rescue_list, const float* __restrict__ pd,
    const int* __restrict__ pi, float* __restrict__ outq,
    float* __restrict__ outidx, float* __restrict__ counts) {
  const int lane = threadIdx.x;
  const int nr = *rescue_n;
  for (int li = blockIdx.x; li < nr; li += gridDim.x) {
    const int row = rescue_list[li];
    float d = (lane < NSLICE) ? pd[li * NSLICE + lane] : 3.5e38f;
    int ix = (lane < NSLICE) ? pi[li * NSLICE + lane] : 0x7fffffff;
#pragma unroll
    for (int m = 1; m < NSLICE; m <<= 1) {
      float od = __shfl_xor(d, m, 64);
      int oi = __shfl_xor(ix, m, 64);
      if (od < d || (od == d && oi < ix)) { d = od; ix = oi; }
    }
    int bfin = __shfl(ix, 0, 64);
    if (lane == 0) {
      outidx[row] = (float)bfin;
      atomicAdd(&counts[bfin], 1.0f);
    }
    outq[(size_t)row * D + lane] = dcb[(size_t)bfin * D + lane];
  }
}

// ---------------- Kernel 5: perplexity ----------------------------------------
__global__ __launch_bounds__(256) void vq_perp_kernel(
    const float* __restrict__ counts, float* __restrict__ out, int E, float invN) {
  __shared__ float red[4];
  float s = 0.f;
  for (int j = threadIdx.x; j < E; j += 256) {
    float p = counts[j] * invN;
    s += p * logf(p + 1e-10f);
  }
#pragma unroll
  for (int off = 32; off > 0; off >>= 1) s += __shfl_down(s, off, 64);
  int wid = threadIdx.x >> 6;
  if ((threadIdx.x & 63) == 0) red[wid] = s;
  __syncthreads();
  if (threadIdx.x == 0) {
    float t = (red[0] + red[1]) + (red[2] + red[3]);
    out[0] = expf(-t);
  }
}

static inline size_t align256(size_t x) { return (x + 255) & ~(size_t)255; }

extern "C" void kernel_launch(void* const* d_in, const int* in_sizes, int n_in,
                              void* d_out, int out_size, void* d_ws, size_t ws_size,
                              hipStream_t stream) {
  const float* X      = (const float*)d_in[0];
  const float* cb     = (const float*)d_in[1];
  const float* dither = (const float*)d_in[2];

  const int N   = in_sizes[0] / D;  // 65536
  const int E   = in_sizes[1] / D;  // 4096
  const int Em1 = in_sizes[2];      // 4095

  char* w = (char*)d_ws;
  float* dcb            = (float*)w;          w += align256((size_t)E_PAD * D * sizeof(float));
  unsigned short* dcbh  = (unsigned short*)w; w += align256((size_t)E_PAD * D * sizeof(short));
  unsigned short* dcbl  = (unsigned short*)w; w += align256((size_t)E_PAD * D * sizeof(short));
  float* c2h            = (float*)w;          w += align256((size_t)E_PAD * sizeof(float));
  float* out_b1         = (float*)w;          w += align256((size_t)ESLICES * N * sizeof(float));
  int* out_i1           = (int*)w;            w += align256((size_t)ESLICES * N * sizeof(int));
  float* out_b2         = (float*)w;          w += align256((size_t)ESLICES * N * sizeof(float));
  float* counts         = (float*)w;          w += align256((size_t)E_PAD * sizeof(float));
  int* rescue_n         = (int*)w;            w += align256(sizeof(int));
  int* rescue_list      = (int*)w;            w += align256((size_t)N * sizeof(int));
  float* pd             = (float*)w;          w += align256((size_t)N * NSLICE * sizeof(float));
  int* pi               = (int*)w;            w += align256((size_t)N * NSLICE * sizeof(int));

  float* outq   = (float*)d_out;
  float* perp   = (float*)d_out + (size_t)N * D;
  float* outidx = (float*)d_out + (size_t)N * D + 1;

  build_kernel<<<E_PAD / 4, 256, 0, stream>>>(cb, dither, dcb, dcbh, dcbl, c2h,
                                              counts, rescue_n, E, Em1);

  dim3 g2(N / 128, ESLICES);
  vq_mfma_kernel<<<g2, BLK, 0, stream>>>(X, dcbh, dcbl, c2h, out_b1, out_i1, out_b2, N);

  finish_kernel<<<N / 64, 64, 0, stream>>>(out_b1, out_i1, out_b2, dcb, outq, outidx,
                                           counts, rescue_n, rescue_list, N);

  rescue_scan_kernel<<<2048, 64, 0, stream>>>(X, dcb, c2h, rescue_n, rescue_list, pd, pi);

  rescue_fin_kernel<<<1024, 64, 0, stream>>>(dcb, rescue_n, rescue_list, pd, pi,
                                             outq, outidx, counts);

  vq_perp_kernel<<<1, 256, 0, stream>>>(counts, perp, E, 1.0f / (float)N);
}